// Round 8
// baseline (181.322 us; speedup 1.0000x reference)
//
#include <hip/hip_runtime.h>
#include <hip/hip_bf16.h>

typedef unsigned short u16;
typedef __bf16 bf16_t;
typedef bf16_t bf16x8 __attribute__((ext_vector_type(8)));
typedef float f32x4 __attribute__((ext_vector_type(4)));

// NOTE: csr entries are u16 node ids — requires N < 65536 (problem: N=50000).

// ---------------------------------------------------------------------------
// GEMM core (global A): one wave computes 16 rows x 128 cols of
// A[M,128] @ W[128,128] via 8 col-tiles x 4 k-steps of mfma_f32_16x16x32_bf16.
// B-fragments from prepacked wf (16B/lane contiguous). Same intra-lane k map
// for A and B, so any HW k-permutation cancels.
// ---------------------------------------------------------------------------
template <bool ABF16>
__device__ __forceinline__ void gemm_core(
    const void* __restrict__ Aptr, const u16* __restrict__ wf,
    int M, int row0, int lane, f32x4 acc[8])
{
    const int r  = lane & 15;
    const int kb = lane >> 4;
    int arow = row0 + r;
    int arc  = arow < M ? arow : (M - 1);

    bf16x8 afrag[4];
    if (ABF16) {
        const u16* A = (const u16*)Aptr + (size_t)arc * 128 + kb * 8;
#pragma unroll
        for (int s = 0; s < 4; s++)
            afrag[s] = __builtin_bit_cast(bf16x8, *(const int4*)(A + s * 32));
    } else {
        const float* A = (const float*)Aptr + (size_t)arc * 128 + kb * 8;
#pragma unroll
        for (int s = 0; s < 4; s++) {
            float4 v0 = *(const float4*)(A + s * 32);
            float4 v1 = *(const float4*)(A + s * 32 + 4);
            bf16x8 t;
            t[0] = (bf16_t)v0.x; t[1] = (bf16_t)v0.y;
            t[2] = (bf16_t)v0.z; t[3] = (bf16_t)v0.w;
            t[4] = (bf16_t)v1.x; t[5] = (bf16_t)v1.y;
            t[6] = (bf16_t)v1.z; t[7] = (bf16_t)v1.w;
            afrag[s] = t;
        }
    }

#pragma unroll
    for (int ct = 0; ct < 8; ct++) acc[ct] = (f32x4){0.f, 0.f, 0.f, 0.f};

#pragma unroll
    for (int ct = 0; ct < 8; ct++) {
#pragma unroll
        for (int s = 0; s < 4; s++) {
            bf16x8 bfrag = __builtin_bit_cast(
                bf16x8, *(const int4*)(wf + (((ct << 2) + s) << 9) + (lane << 3)));
            acc[ct] = __builtin_amdgcn_mfma_f32_16x16x32_bf16(
                afrag[s], bfrag, acc[ct], 0, 0, 0);
        }
    }
}

// Epilogue: bias + relu (+ optional BN affine), store bf16.
// C/D layout (m89-verified): col = lane&15, row = (lane>>4)*4 + j
template <bool BN>
__device__ __forceinline__ void gemm_epi_store(
    f32x4 acc[8], const float* __restrict__ bias,
    const float* __restrict__ gamma, const float* __restrict__ beta,
    const float* __restrict__ mmean, const float* __restrict__ mvar,
    u16* __restrict__ obf, int M, int row0, int lane)
{
    const int crow0 = row0 + ((lane >> 4) << 2);
    const int ccol  = lane & 15;
#pragma unroll
    for (int ct = 0; ct < 8; ct++) {
        int col  = (ct << 4) + ccol;
        float b  = bias[col];
        float scale = 1.f, shift = 0.f;
        if (BN) {
            float s_ = gamma[col] / sqrtf(mvar[col] + 1e-3f);
            scale = s_;
            shift = beta[col] - mmean[col] * s_;
        }
#pragma unroll
        for (int j = 0; j < 4; j++) {
            int row = crow0 + j;
            if (row < M) {
                float v = fmaxf(acc[ct][j] + b, 0.f);
                if (BN) v = v * scale + shift;
                obf[(size_t)row * 128 + col] = __builtin_bit_cast(u16, (bf16_t)v);
            }
        }
    }
}

// Block-local exclusive scan of bsum[0..nb) into sb (nb <= 256).
__device__ __forceinline__ void scan_bsum(
    const int* __restrict__ bsum, int nb, int* sb)
{
    int v = (threadIdx.x < (unsigned)nb) ? bsum[threadIdx.x] : 0;
    sb[threadIdx.x] = v;
    __syncthreads();
    for (int off = 1; off < 256; off <<= 1) {
        int t = (threadIdx.x >= (unsigned)off) ? sb[threadIdx.x - off] : 0;
        __syncthreads();
        sb[threadIdx.x] += t;
        __syncthreads();
    }
    int inc = sb[threadIdx.x];
    __syncthreads();
    sb[threadIdx.x] = inc - v;          // exclusive
    __syncthreads();
}

// Deep-batched CSR neighbor gather: up to 8 independent row loads in flight.
__device__ __forceinline__ void gather_node(
    const u16* __restrict__ t, const u16* __restrict__ csr,
    int beg, int end, int c8, float acc[8])
{
    int i = beg;
    while (i + 8 <= end) {
        int idx[8];
#pragma unroll
        for (int u = 0; u < 8; u++) idx[u] = csr[i + u];
        int4 rows[8];
#pragma unroll
        for (int u = 0; u < 8; u++)
            rows[u] = *(const int4*)(t + (size_t)idx[u] * 128 + c8);
#pragma unroll
        for (int u = 0; u < 8; u++) {
            bf16x8 v = __builtin_bit_cast(bf16x8, rows[u]);
#pragma unroll
            for (int j = 0; j < 8; j++) acc[j] += (float)v[j];
        }
        i += 8;
    }
    if (i + 4 <= end) {
        int idx[4];
#pragma unroll
        for (int u = 0; u < 4; u++) idx[u] = csr[i + u];
        int4 rows[4];
#pragma unroll
        for (int u = 0; u < 4; u++)
            rows[u] = *(const int4*)(t + (size_t)idx[u] * 128 + c8);
#pragma unroll
        for (int u = 0; u < 4; u++) {
            bf16x8 v = __builtin_bit_cast(bf16x8, rows[u]);
#pragma unroll
            for (int j = 0; j < 8; j++) acc[j] += (float)v[j];
        }
        i += 4;
    }
    for (; i < end; ++i) {
        int src = csr[i];
        bf16x8 v = __builtin_bit_cast(bf16x8,
            *(const int4*)(t + (size_t)src * 128 + c8));
#pragma unroll
        for (int j = 0; j < 8; j++) acc[j] += (float)v[j];
    }
}

// ---------------------------------------------------------------------------
// Dispatch Z: zero deg/out, head = -1.
// ---------------------------------------------------------------------------
__global__ __launch_bounds__(256) void zerok(
    int* __restrict__ deg, int* __restrict__ head,
    float* __restrict__ out, int N, int outsz)
{
    int i = blockIdx.x * 256 + threadIdx.x;
    if (i < N) { deg[i] = 0; head[i] = -1; }
    if (i < outsz) out[i] = 0.f;
}

// ---------------------------------------------------------------------------
// Dispatch A: weight-fragment pre-pack || (degree histogram + per-dst linked
// list). The nl store is indexed by edge id -> fully coalesced; no random
// stores anywhere in the graph build now.
// ---------------------------------------------------------------------------
__global__ __launch_bounds__(256) void fusedA(
    const float* __restrict__ W1, const float* __restrict__ W2,
    const float* __restrict__ W3, const float* __restrict__ W4,
    u16* __restrict__ wf, const int* __restrict__ ei,
    int* __restrict__ deg, int* __restrict__ head, int2* __restrict__ nl,
    int E)
{
    if (blockIdx.x < 256) {
        int idx = blockIdx.x * 256 + threadIdx.x;          // 0..65535
        const float* Ws[4] = {W1, W2, W3, W4};
        int w  = idx >> 14;
        int e  = idx & 16383;
        int i  = e & 7;
        int l  = (e >> 3) & 63;
        int s  = (e >> 9) & 3;
        int ct = (e >> 11) & 7;
        int row = 32 * s + 8 * (l >> 4) + i;
        int col = 16 * ct + (l & 15);
        float v = Ws[w][row * 128 + col];
        wf[idx] = __builtin_bit_cast(u16, (bf16_t)v);
    } else {
        int e = (blockIdx.x - 256) * 256 + threadIdx.x;
        if (e < E) {
            int2 p = ((const int2*)ei)[e];
            atomicAdd(&deg[p.y], 1);
            int old = atomicExch(&head[p.y], e);
            nl[e] = make_int2(old, p.x);       // coalesced 8B store
        }
    }
}

// ---------------------------------------------------------------------------
// Dispatch B: GEMM1 (x f32 -> h1 bf16, BN1)  ||  scan1 (deg -> rs, bsum).
// ---------------------------------------------------------------------------
__global__ __launch_bounds__(256) void fusedB(
    const float* __restrict__ x, const u16* __restrict__ wf,
    const float* __restrict__ b1, const float* __restrict__ g1,
    const float* __restrict__ be1, const float* __restrict__ mm1,
    const float* __restrict__ mv1, u16* __restrict__ h1, int M,
    const int* __restrict__ deg, int* __restrict__ rs, int* __restrict__ bsum,
    int N, int gb)
{
    if ((int)blockIdx.x < gb) {
        int lane = threadIdx.x & 63, wv = threadIdx.x >> 6;
        int row0 = (blockIdx.x * 4 + wv) * 16;
        f32x4 acc[8];
        gemm_core<false>(x, wf, M, row0, lane, acc);
        gemm_epi_store<true>(acc, b1, g1, be1, mm1, mv1, h1, M, row0, lane);
    } else {
        __shared__ int sh[256];
        int blk = blockIdx.x - gb;
        int i = blk * 256 + threadIdx.x;
        int v = (i < N) ? deg[i] : 0;
        sh[threadIdx.x] = v;
        __syncthreads();
        for (int off = 1; off < 256; off <<= 1) {
            int t = (threadIdx.x >= (unsigned)off) ? sh[threadIdx.x - off] : 0;
            __syncthreads();
            sh[threadIdx.x] += t;
            __syncthreads();
        }
        if (i < N) rs[i] = sh[threadIdx.x] - v;          // block-local exclusive
        if (threadIdx.x == 255) bsum[blk] = sh[255];
    }
}

// ---------------------------------------------------------------------------
// Dispatch C: GEMM2 (h1 -> tb, no BN)  ||  linked-list walk -> contiguous u16
// CSR rows (+ rsa). One thread per node; consecutive nodes write consecutive
// csr ranges -> stores assemble into full lines (no sector amplification).
// ---------------------------------------------------------------------------
__global__ __launch_bounds__(256) void fusedC(
    const u16* __restrict__ h1, const u16* __restrict__ wf,
    const float* __restrict__ b2, u16* __restrict__ tb, int M,
    const int* __restrict__ rs, const int* __restrict__ bsum,
    const int* __restrict__ head, const int2* __restrict__ nl,
    u16* __restrict__ csr, int* __restrict__ rsa,
    int E, int N, int nb, int gb)
{
    if ((int)blockIdx.x < gb) {
        int lane = threadIdx.x & 63, wv = threadIdx.x >> 6;
        int row0 = (blockIdx.x * 4 + wv) * 16;
        f32x4 acc[8];
        gemm_core<true>(h1, wf, M, row0, lane, acc);
        gemm_epi_store<false>(acc, b2, nullptr, nullptr, nullptr, nullptr,
                              tb, M, row0, lane);
    } else {
        __shared__ int sb[256];
        scan_bsum(bsum, nb, sb);
        int blk = blockIdx.x - gb;
        int n = blk * 256 + threadIdx.x;
        if (n < N) {
            int base = rs[n] + sb[n >> 8];
            rsa[n] = base;
            int ptr = head[n];
            while (ptr >= 0) {
                int2 v = nl[ptr];
                csr[base++] = (u16)v.y;
                ptr = v.x;
            }
        }
        if (blk == 0 && threadIdx.x == 0) rsa[N] = E;
    }
}

// ---------------------------------------------------------------------------
// Dispatches D/E: fused GIN-aggregate + GEMM.
// Phase 1: block gathers its 64 rows' neighborhoods (self + CSR neighbors,
//   8-deep batched loads) into an XOR-swizzled LDS A-tile:
//   byte = rl*256 + ((c ^ (rl&7)) << 4)  (2-way bank aliasing = free, m136).
// Phase 2: MFMA from LDS.
// Epilogue: BN store (D) or LDS-staged group reduction (E).
// ---------------------------------------------------------------------------
template <bool BN_, bool RED>
__global__ __launch_bounds__(256) void aggGemm(
    const u16* __restrict__ t, const int* __restrict__ rsa,
    const u16* __restrict__ csr,
    const u16* __restrict__ wf, const float* __restrict__ bias,
    const float* __restrict__ gamma, const float* __restrict__ beta,
    const float* __restrict__ mmean, const float* __restrict__ mvar,
    u16* __restrict__ obf, const int* __restrict__ batch,
    float* __restrict__ out, int N, int E)
{
    constexpr int GSPAN = 20;
    __shared__ u16 ldsA[64 * 128];
    __shared__ float grp[RED ? (GSPAN * 128) : 1];

    const int row0blk = blockIdx.x * 64;
    const int sub = threadIdx.x >> 4;       // 0..15: node within pass
    const int c   = threadIdx.x & 15;       // 16B chunk within row
    const int c8  = c << 3;

#pragma unroll
    for (int pass = 0; pass < 4; pass++) {
        int rl   = pass * 16 + sub;         // 0..63 local row
        int node = row0blk + rl;
        float acc[8];
        if (node < N) {
            bf16x8 s8 = __builtin_bit_cast(
                bf16x8, *(const int4*)(t + (size_t)node * 128 + c8));
#pragma unroll
            for (int j = 0; j < 8; j++) acc[j] = (float)s8[j];
            gather_node(t, csr, rsa[node], rsa[node + 1], c8, acc);
        } else {
#pragma unroll
            for (int j = 0; j < 8; j++) acc[j] = 0.f;
        }
        bf16x8 o;
#pragma unroll
        for (int j = 0; j < 8; j++) o[j] = (bf16_t)acc[j];
        *(int4*)((char*)ldsA + rl * 256 + ((c ^ (rl & 7)) << 4)) =
            __builtin_bit_cast(int4, o);
    }

    if (RED) {
        for (int i = threadIdx.x; i < GSPAN * 128; i += 256) grp[i] = 0.f;
    }
    __syncthreads();

    // ---- GEMM from swizzled LDS ----
    const int lane = threadIdx.x & 63;
    const int wv   = threadIdx.x >> 6;
    const int r    = lane & 15;
    const int kb   = lane >> 4;
    const int rl   = wv * 16 + r;

    bf16x8 afrag[4];
#pragma unroll
    for (int s = 0; s < 4; s++)
        afrag[s] = __builtin_bit_cast(
            bf16x8, *(const int4*)((const char*)ldsA + rl * 256 +
                                   ((((s << 2) + kb) ^ (rl & 7)) << 4)));

    f32x4 acc[8];
#pragma unroll
    for (int ct = 0; ct < 8; ct++) acc[ct] = (f32x4){0.f, 0.f, 0.f, 0.f};
#pragma unroll
    for (int ct = 0; ct < 8; ct++) {
#pragma unroll
        for (int s = 0; s < 4; s++) {
            bf16x8 bfrag = __builtin_bit_cast(
                bf16x8, *(const int4*)(wf + (((ct << 2) + s) << 9) + (lane << 3)));
            acc[ct] = __builtin_amdgcn_mfma_f32_16x16x32_bf16(
                afrag[s], bfrag, acc[ct], 0, 0, 0);
        }
    }

    const int row0 = row0blk + wv * 16;
    if constexpr (!RED) {
        gemm_epi_store<BN_>(acc, bias, gamma, beta, mmean, mvar, obf, N, row0, lane);
    } else {
        int gfirst = batch[row0blk];
        int lastr  = row0blk + 63 < N - 1 ? row0blk + 63 : N - 1;
        int glast  = batch[lastr];
        const int crow0 = row0 + ((lane >> 4) << 2);
        const int ccol  = lane & 15;
        int bj[4];
#pragma unroll
        for (int j = 0; j < 4; j++) {
            int row = crow0 + j;
            bj[j] = (row < N) ? batch[row] : -1;
        }
        if (glast - gfirst < GSPAN) {
#pragma unroll
            for (int ct = 0; ct < 8; ct++) {
                int col = (ct << 4) + ccol;
                float b = bias[col];
                float run = 0.f;
                int gp = -1;
#pragma unroll
                for (int j = 0; j < 4; j++) {
                    if (bj[j] < 0) continue;
                    float v = fmaxf(acc[ct][j] + b, 0.f);
                    if (bj[j] != gp) {
                        if (gp >= 0) atomicAdd(&grp[(gp - gfirst) * 128 + col], run);
                        run = 0.f;
                        gp  = bj[j];
                    }
                    run += v;
                }
                if (gp >= 0) atomicAdd(&grp[(gp - gfirst) * 128 + col], run);
            }
            __syncthreads();
            int span = glast - gfirst + 1;
            for (int i = threadIdx.x; i < span * 128; i += 256) {
                float v = grp[i];
                if (v != 0.f) atomicAdd(out + (size_t)gfirst * 128 + i, v);
            }
        } else {
            // pathological tiny-group fallback: direct global atomics
#pragma unroll
            for (int ct = 0; ct < 8; ct++) {
                int col = (ct << 4) + ccol;
                float b = bias[col];
                float run = 0.f;
                int gp = -1;
#pragma unroll
                for (int j = 0; j < 4; j++) {
                    if (bj[j] < 0) continue;
                    float v = fmaxf(acc[ct][j] + b, 0.f);
                    if (bj[j] != gp) {
                        if (gp >= 0) atomicAdd(out + (size_t)gp * 128 + col, run);
                        run = 0.f;
                        gp  = bj[j];
                    }
                    run += v;
                }
                if (gp >= 0) atomicAdd(out + (size_t)gp * 128 + col, run);
            }
        }
    }
}

// ---------------------------------------------------------------------------
static inline size_t al256(size_t x) { return (x + 255) & ~(size_t)255; }

extern "C" void kernel_launch(void* const* d_in, const int* in_sizes, int n_in,
                              void* d_out, int out_size, void* d_ws, size_t ws_size,
                              hipStream_t stream)
{
    const float* x   = (const float*)d_in[0];
    const int*   ei  = (const int*)d_in[1];
    const int*   bat = (const int*)d_in[2];
    const float* W1  = (const float*)d_in[3];
    const float* b1  = (const float*)d_in[4];
    const float* g1  = (const float*)d_in[5];
    const float* be1 = (const float*)d_in[6];
    const float* mm1 = (const float*)d_in[7];
    const float* mv1 = (const float*)d_in[8];
    const float* W2  = (const float*)d_in[9];
    const float* b2  = (const float*)d_in[10];
    const float* W3  = (const float*)d_in[11];
    const float* b3  = (const float*)d_in[12];
    const float* g2  = (const float*)d_in[13];
    const float* be2 = (const float*)d_in[14];
    const float* mm2 = (const float*)d_in[15];
    const float* mv2 = (const float*)d_in[16];
    const float* W4  = (const float*)d_in[17];
    const float* b4  = (const float*)d_in[18];
    float* out = (float*)d_out;

    const int N  = in_sizes[0] / 128;
    const int E  = in_sizes[1] / 2;
    const int nb = (N + 255) / 256;
    const int eb = (E + 255) / 256;
    const int gb = (N + 63) / 64;

    char* ws = (char*)d_ws;
    size_t off = 0;
    u16*   wf   = (u16*)(ws + off);  off += al256(4 * 16384 * sizeof(u16));
    u16*   h1   = (u16*)(ws + off);  off += al256((size_t)N * 128 * sizeof(u16));
    u16*   tb   = (u16*)(ws + off);  off += al256((size_t)N * 128 * sizeof(u16));
    int*   rs   = (int*)(ws + off);  off += al256((size_t)N * sizeof(int));
    int*   rsa  = (int*)(ws + off);  off += al256((size_t)(N + 1) * sizeof(int));
    int*   deg  = (int*)(ws + off);  off += al256((size_t)N * sizeof(int));
    int*   head = (int*)(ws + off);  off += al256((size_t)N * sizeof(int));
    int*   bsum = (int*)(ws + off);  off += al256((size_t)nb * sizeof(int));
    u16*   csr  = (u16*)(ws + off);  off += al256((size_t)E * sizeof(u16));
    int2*  nl   = (int2*)(ws + off); off += al256((size_t)E * sizeof(int2));

    // Z: zero deg/out, head=-1
    zerok<<<nb, 256, 0, stream>>>(deg, head, out, N, out_size);
    // A: wfrag pack || hist + linked-list build
    fusedA<<<256 + eb, 256, 0, stream>>>(W1, W2, W3, W4, wf, ei, deg, head, nl, E);
    // B: GEMM1 || scan1
    fusedB<<<gb + nb, 256, 0, stream>>>(x, wf, b1, g1, be1, mm1, mv1, h1, N,
                                        deg, rs, bsum, N, gb);
    // C: GEMM2 || list-walk -> csr + rsa
    fusedC<<<gb + nb, 256, 0, stream>>>(h1, wf + 16384, b2, tb, N,
                                        rs, bsum, head, nl, csr, rsa,
                                        E, N, nb, gb);
    // D: h1 = bn2(relu( (tb + gather(tb)) @ W3 + b3 ))
    aggGemm<true, false><<<gb, 256, 0, stream>>>(
        tb, rsa, csr, wf + 2 * 16384, b3, g2, be2, mm2, mv2,
        h1, nullptr, nullptr, N, E);
    // E: out += group-reduce relu( (h1 + gather(h1)) @ W4 + b4 )
    aggGemm<false, true><<<gb, 256, 0, stream>>>(
        h1, rsa, csr, wf + 3 * 16384, b4, nullptr, nullptr, nullptr, nullptr,
        nullptr, bat, out, N, E);
}

// Round 9
// 159.136 us; speedup vs baseline: 1.1394x; 1.1394x over previous
//
#include <hip/hip_runtime.h>
#include <hip/hip_bf16.h>

typedef unsigned short u16;
typedef unsigned int u32;
typedef __bf16 bf16_t;
typedef bf16_t bf16x8 __attribute__((ext_vector_type(8)));
typedef float f32x4 __attribute__((ext_vector_type(4)));

// Graph build is a two-level counting partition: edges -> 64-node bins
// (bin = dst>>6, one bin per aggGemm block). ALL returning atomics are LDS;
// zero per-edge global atomics (memory-side atomic wall = ~64B HBM granule
// per op, measured rounds 7/8 at ~45-57us for 640K ops).
#define EB 32            // edge-partition blocks
#define ECAP 1536        // max edges per 64-node bin (mean 816, sd ~29)

// ---------------------------------------------------------------------------
// GEMM core (global A): one wave computes 16 rows x 128 cols of
// A[M,128] @ W[128,128] via 8 col-tiles x 4 k-steps of mfma_f32_16x16x32_bf16.
// B-fragments from prepacked wf (16B/lane contiguous). Same intra-lane k map
// for A and B, so any HW k-permutation cancels.
// ---------------------------------------------------------------------------
template <bool ABF16>
__device__ __forceinline__ void gemm_core(
    const void* __restrict__ Aptr, const u16* __restrict__ wf,
    int M, int row0, int lane, f32x4 acc[8])
{
    const int r  = lane & 15;
    const int kb = lane >> 4;
    int arow = row0 + r;
    int arc  = arow < M ? arow : (M - 1);

    bf16x8 afrag[4];
    if (ABF16) {
        const u16* A = (const u16*)Aptr + (size_t)arc * 128 + kb * 8;
#pragma unroll
        for (int s = 0; s < 4; s++)
            afrag[s] = __builtin_bit_cast(bf16x8, *(const int4*)(A + s * 32));
    } else {
        const float* A = (const float*)Aptr + (size_t)arc * 128 + kb * 8;
#pragma unroll
        for (int s = 0; s < 4; s++) {
            float4 v0 = *(const float4*)(A + s * 32);
            float4 v1 = *(const float4*)(A + s * 32 + 4);
            bf16x8 t;
            t[0] = (bf16_t)v0.x; t[1] = (bf16_t)v0.y;
            t[2] = (bf16_t)v0.z; t[3] = (bf16_t)v0.w;
            t[4] = (bf16_t)v1.x; t[5] = (bf16_t)v1.y;
            t[6] = (bf16_t)v1.z; t[7] = (bf16_t)v1.w;
            afrag[s] = t;
        }
    }

#pragma unroll
    for (int ct = 0; ct < 8; ct++) acc[ct] = (f32x4){0.f, 0.f, 0.f, 0.f};

#pragma unroll
    for (int ct = 0; ct < 8; ct++) {
#pragma unroll
        for (int s = 0; s < 4; s++) {
            bf16x8 bfrag = __builtin_bit_cast(
                bf16x8, *(const int4*)(wf + (((ct << 2) + s) << 9) + (lane << 3)));
            acc[ct] = __builtin_amdgcn_mfma_f32_16x16x32_bf16(
                afrag[s], bfrag, acc[ct], 0, 0, 0);
        }
    }
}

// Epilogue: bias + relu (+ optional BN affine), store bf16.
// C/D layout (m89-verified): col = lane&15, row = (lane>>4)*4 + j
template <bool BN>
__device__ __forceinline__ void gemm_epi_store(
    f32x4 acc[8], const float* __restrict__ bias,
    const float* __restrict__ gamma, const float* __restrict__ beta,
    const float* __restrict__ mmean, const float* __restrict__ mvar,
    u16* __restrict__ obf, int M, int row0, int lane)
{
    const int crow0 = row0 + ((lane >> 4) << 2);
    const int ccol  = lane & 15;
#pragma unroll
    for (int ct = 0; ct < 8; ct++) {
        int col  = (ct << 4) + ccol;
        float b  = bias[col];
        float scale = 1.f, shift = 0.f;
        if (BN) {
            float s_ = gamma[col] / sqrtf(mvar[col] + 1e-3f);
            scale = s_;
            shift = beta[col] - mmean[col] * s_;
        }
#pragma unroll
        for (int j = 0; j < 4; j++) {
            int row = crow0 + j;
            if (row < M) {
                float v = fmaxf(acc[ct][j] + b, 0.f);
                if (BN) v = v * scale + shift;
                obf[(size_t)row * 128 + col] = __builtin_bit_cast(u16, (bf16_t)v);
            }
        }
    }
}

// ---------------------------------------------------------------------------
// Dispatch A: wpack (256 blk) || p1hist (EB blk) || zero out (rest).
// ---------------------------------------------------------------------------
__global__ __launch_bounds__(256) void fusedA(
    const float* __restrict__ W1, const float* __restrict__ W2,
    const float* __restrict__ W3, const float* __restrict__ W4,
    u16* __restrict__ wf, const int2* __restrict__ ei,
    int* __restrict__ hcnt, float* __restrict__ out,
    int E, int nbin, int epb, int outsz)
{
    if (blockIdx.x < 256) {
        int idx = blockIdx.x * 256 + threadIdx.x;          // 0..65535
        const float* Ws[4] = {W1, W2, W3, W4};
        int w  = idx >> 14;
        int e  = idx & 16383;
        int i  = e & 7;
        int l  = (e >> 3) & 63;
        int s  = (e >> 9) & 3;
        int ct = (e >> 11) & 7;
        int row = 32 * s + 8 * (l >> 4) + i;
        int col = 16 * ct + (l & 15);
        float v = Ws[w][row * 128 + col];
        wf[idx] = __builtin_bit_cast(u16, (bf16_t)v);
    } else if ((int)blockIdx.x < 256 + EB) {
        __shared__ int h[800];
        int b = blockIdx.x - 256;
        for (int i = threadIdx.x; i < nbin; i += 256) h[i] = 0;
        __syncthreads();
        int e0 = b * epb, e1 = min(e0 + epb, E);
        for (int e = e0 + threadIdx.x; e < e1; e += 256) {
            int2 p = ei[e];
            atomicAdd(&h[p.y >> 6], 1);               // LDS atomic
        }
        __syncthreads();
        for (int i = threadIdx.x; i < nbin; i += 256)
            hcnt[b * nbin + i] = h[i];
    } else {
        int i = (blockIdx.x - 256 - EB) * 256 + threadIdx.x;
        if (i < outsz) out[i] = 0.f;
    }
}

// ---------------------------------------------------------------------------
// Dispatch B: GEMM1 (x f32 -> h1 bf16, BN1)  ||  scank (1 block):
// column totals -> exclusive scan -> segstart + per-(block,bin) bases.
// ---------------------------------------------------------------------------
__global__ __launch_bounds__(256) void fusedB(
    const float* __restrict__ x, const u16* __restrict__ wf,
    const float* __restrict__ b1, const float* __restrict__ g1,
    const float* __restrict__ be1, const float* __restrict__ mm1,
    const float* __restrict__ mv1, u16* __restrict__ h1, int M,
    const int* __restrict__ hcnt, int* __restrict__ basem,
    int* __restrict__ segstart, int E, int nbin, int gb)
{
    if ((int)blockIdx.x < gb) {
        int lane = threadIdx.x & 63, wv = threadIdx.x >> 6;
        int row0 = (blockIdx.x * 4 + wv) * 16;
        f32x4 acc[8];
        gemm_core<false>(x, wf, M, row0, lane, acc);
        gemm_epi_store<true>(acc, b1, g1, be1, mm1, mv1, h1, M, row0, lane);
    } else {
        __shared__ int tot[800];
        for (int bin = threadIdx.x; bin < nbin; bin += 256) {
            int s = 0;
            for (int b = 0; b < EB; b++) s += hcnt[b * nbin + bin];
            tot[bin] = s;
        }
        __syncthreads();
        if (threadIdx.x == 0) {
            int run = 0;
            for (int i = 0; i < nbin; i++) { int v = tot[i]; tot[i] = run; run += v; }
            segstart[nbin] = E;
        }
        __syncthreads();
        for (int bin = threadIdx.x; bin < nbin; bin += 256) {
            segstart[bin] = tot[bin];
            int run = tot[bin];
            for (int b = 0; b < EB; b++) {
                basem[b * nbin + bin] = run;
                run += hcnt[b * nbin + bin];
            }
        }
    }
}

// ---------------------------------------------------------------------------
// Dispatch C: GEMM2 (h1 -> tb, no BN)  ||  p1scat (EB blocks): stream edges,
// slot from LDS running counters seeded with reserved bases, write packed
// (dstLocal<<16)|src. Same-bin edges per block -> consecutive slots.
// ---------------------------------------------------------------------------
__global__ __launch_bounds__(256) void fusedC(
    const u16* __restrict__ h1, const u16* __restrict__ wf,
    const float* __restrict__ b2, u16* __restrict__ tb, int M,
    const int2* __restrict__ ei, const int* __restrict__ basem,
    u32* __restrict__ eseg, int E, int nbin, int epb, int gb)
{
    if ((int)blockIdx.x < gb) {
        int lane = threadIdx.x & 63, wv = threadIdx.x >> 6;
        int row0 = (blockIdx.x * 4 + wv) * 16;
        f32x4 acc[8];
        gemm_core<true>(h1, wf, M, row0, lane, acc);
        gemm_epi_store<false>(acc, b2, nullptr, nullptr, nullptr, nullptr,
                              tb, M, row0, lane);
    } else {
        __shared__ int run[800];
        int b = blockIdx.x - gb;
        for (int i = threadIdx.x; i < nbin; i += 256)
            run[i] = basem[b * nbin + i];
        __syncthreads();
        int e0 = b * epb, e1 = min(e0 + epb, E);
        for (int e = e0 + threadIdx.x; e < e1; e += 256) {
            int2 p = ei[e];
            int bin = p.y >> 6;
            int pos = atomicAdd(&run[bin], 1);        // LDS atomic
            eseg[pos] = ((u32)(p.y & 63) << 16) | (u32)p.x;
        }
    }
}

// ---------------------------------------------------------------------------
// Dispatches D/E: fused GIN-aggregate + GEMM.
// Phase 0: load this bin's edge segment, LDS counting-sort by dstLocal.
// Phase 1: 16-lane-per-node deep-batched row gathers (src ids from LDS)
//   accumulated with the self term, written to XOR-swizzled LDS A-tile.
// Phase 2: MFMA from LDS.  Epilogue: BN store (D) or group reduction (E).
// ---------------------------------------------------------------------------
template <bool BN_, bool RED>
__global__ __launch_bounds__(256) void aggGemm(
    const u16* __restrict__ t, const int* __restrict__ segstart,
    const u32* __restrict__ eseg,
    const u16* __restrict__ wf, const float* __restrict__ bias,
    const float* __restrict__ gamma, const float* __restrict__ beta,
    const float* __restrict__ mmean, const float* __restrict__ mvar,
    u16* __restrict__ obf, const int* __restrict__ batch,
    float* __restrict__ out, int N)
{
    constexpr int GSPAN = 20;
    __shared__ u16 ldsA[64 * 128];
    __shared__ u32 ebuf[ECAP];
    __shared__ u16 slist[ECAP];
    __shared__ int cnt[64];
    __shared__ int sstart[65];
    __shared__ float grp[RED ? (GSPAN * 128) : 1];

    const int row0blk = blockIdx.x * 64;

    // ---- Phase 0: local counting sort of this bin's edges ----
    int segb = segstart[blockIdx.x];
    int k    = segstart[blockIdx.x + 1] - segb;
    if (k > ECAP) k = ECAP;              // impossible statistically; safety
    if (threadIdx.x < 64) cnt[threadIdx.x] = 0;
    __syncthreads();
    for (int i = threadIdx.x; i < k; i += 256) {
        u32 v = eseg[segb + i];
        ebuf[i] = v;
        atomicAdd(&cnt[v >> 16], 1);
    }
    __syncthreads();
    if (threadIdx.x == 0) {
        int run = 0;
#pragma unroll
        for (int d = 0; d < 64; d++) {
            sstart[d] = run;
            run += cnt[d];
            cnt[d] = sstart[d];          // becomes running placement counter
        }
        sstart[64] = run;
    }
    __syncthreads();
    for (int i = threadIdx.x; i < k; i += 256) {
        u32 v = ebuf[i];
        int pos = atomicAdd(&cnt[v >> 16], 1);
        slist[pos] = (u16)(v & 0xffffu);
    }
    __syncthreads();

    // ---- Phase 1: gather rows into swizzled LDS A-tile ----
    const int sub = threadIdx.x >> 4;       // 0..15: node within pass
    const int c   = threadIdx.x & 15;       // 16B chunk within row
    const int c8  = c << 3;

#pragma unroll
    for (int pass = 0; pass < 4; pass++) {
        int rl   = pass * 16 + sub;         // 0..63 local row
        int node = row0blk + rl;
        float acc[8];
        if (node < N) {
            bf16x8 s8 = __builtin_bit_cast(
                bf16x8, *(const int4*)(t + (size_t)node * 128 + c8));
#pragma unroll
            for (int j = 0; j < 8; j++) acc[j] = (float)s8[j];

            int i = sstart[rl], end = sstart[rl + 1];
            while (i + 8 <= end) {
                int idx[8];
#pragma unroll
                for (int u = 0; u < 8; u++) idx[u] = slist[i + u];
                int4 rows[8];
#pragma unroll
                for (int u = 0; u < 8; u++)
                    rows[u] = *(const int4*)(t + (size_t)idx[u] * 128 + c8);
#pragma unroll
                for (int u = 0; u < 8; u++) {
                    bf16x8 v = __builtin_bit_cast(bf16x8, rows[u]);
#pragma unroll
                    for (int j = 0; j < 8; j++) acc[j] += (float)v[j];
                }
                i += 8;
            }
            if (i + 4 <= end) {
                int idx[4];
#pragma unroll
                for (int u = 0; u < 4; u++) idx[u] = slist[i + u];
                int4 rows[4];
#pragma unroll
                for (int u = 0; u < 4; u++)
                    rows[u] = *(const int4*)(t + (size_t)idx[u] * 128 + c8);
#pragma unroll
                for (int u = 0; u < 4; u++) {
                    bf16x8 v = __builtin_bit_cast(bf16x8, rows[u]);
#pragma unroll
                    for (int j = 0; j < 8; j++) acc[j] += (float)v[j];
                }
                i += 4;
            }
            for (; i < end; ++i) {
                int src = slist[i];
                bf16x8 v = __builtin_bit_cast(bf16x8,
                    *(const int4*)(t + (size_t)src * 128 + c8));
#pragma unroll
                for (int j = 0; j < 8; j++) acc[j] += (float)v[j];
            }
        } else {
#pragma unroll
            for (int j = 0; j < 8; j++) acc[j] = 0.f;
        }
        bf16x8 o;
#pragma unroll
        for (int j = 0; j < 8; j++) o[j] = (bf16_t)acc[j];
        *(int4*)((char*)ldsA + rl * 256 + ((c ^ (rl & 7)) << 4)) =
            __builtin_bit_cast(int4, o);
    }

    if (RED) {
        for (int i = threadIdx.x; i < GSPAN * 128; i += 256) grp[i] = 0.f;
    }
    __syncthreads();

    // ---- Phase 2: GEMM from swizzled LDS ----
    const int lane = threadIdx.x & 63;
    const int wv   = threadIdx.x >> 6;
    const int r    = lane & 15;
    const int kb   = lane >> 4;
    const int rl   = wv * 16 + r;

    bf16x8 afrag[4];
#pragma unroll
    for (int s = 0; s < 4; s++)
        afrag[s] = __builtin_bit_cast(
            bf16x8, *(const int4*)((const char*)ldsA + rl * 256 +
                                   ((((s << 2) + kb) ^ (rl & 7)) << 4)));

    f32x4 acc[8];
#pragma unroll
    for (int ct = 0; ct < 8; ct++) acc[ct] = (f32x4){0.f, 0.f, 0.f, 0.f};
#pragma unroll
    for (int ct = 0; ct < 8; ct++) {
#pragma unroll
        for (int s = 0; s < 4; s++) {
            bf16x8 bfrag = __builtin_bit_cast(
                bf16x8, *(const int4*)(wf + (((ct << 2) + s) << 9) + (lane << 3)));
            acc[ct] = __builtin_amdgcn_mfma_f32_16x16x32_bf16(
                afrag[s], bfrag, acc[ct], 0, 0, 0);
        }
    }

    const int row0 = row0blk + wv * 16;
    if constexpr (!RED) {
        gemm_epi_store<BN_>(acc, bias, gamma, beta, mmean, mvar, obf, N, row0, lane);
    } else {
        int gfirst = batch[row0blk];
        int lastr  = row0blk + 63 < N - 1 ? row0blk + 63 : N - 1;
        int glast  = batch[lastr];
        const int crow0 = row0 + ((lane >> 4) << 2);
        const int ccol  = lane & 15;
        int bj[4];
#pragma unroll
        for (int j = 0; j < 4; j++) {
            int row = crow0 + j;
            bj[j] = (row < N) ? batch[row] : -1;
        }
        if (glast - gfirst < GSPAN) {
#pragma unroll
            for (int ct = 0; ct < 8; ct++) {
                int col = (ct << 4) + ccol;
                float b = bias[col];
                float run = 0.f;
                int gp = -1;
#pragma unroll
                for (int j = 0; j < 4; j++) {
                    if (bj[j] < 0) continue;
                    float v = fmaxf(acc[ct][j] + b, 0.f);
                    if (bj[j] != gp) {
                        if (gp >= 0) atomicAdd(&grp[(gp - gfirst) * 128 + col], run);
                        run = 0.f;
                        gp  = bj[j];
                    }
                    run += v;
                }
                if (gp >= 0) atomicAdd(&grp[(gp - gfirst) * 128 + col], run);
            }
            __syncthreads();
            int span = glast - gfirst + 1;
            for (int i = threadIdx.x; i < span * 128; i += 256) {
                float v = grp[i];
                if (v != 0.f) atomicAdd(out + (size_t)gfirst * 128 + i, v);
            }
        } else {
#pragma unroll
            for (int ct = 0; ct < 8; ct++) {
                int col = (ct << 4) + ccol;
                float b = bias[col];
                float run = 0.f;
                int gp = -1;
#pragma unroll
                for (int j = 0; j < 4; j++) {
                    if (bj[j] < 0) continue;
                    float v = fmaxf(acc[ct][j] + b, 0.f);
                    if (bj[j] != gp) {
                        if (gp >= 0) atomicAdd(out + (size_t)gp * 128 + col, run);
                        run = 0.f;
                        gp  = bj[j];
                    }
                    run += v;
                }
                if (gp >= 0) atomicAdd(out + (size_t)gp * 128 + col, run);
            }
        }
    }
}

// ---------------------------------------------------------------------------
static inline size_t al256(size_t x) { return (x + 255) & ~(size_t)255; }

extern "C" void kernel_launch(void* const* d_in, const int* in_sizes, int n_in,
                              void* d_out, int out_size, void* d_ws, size_t ws_size,
                              hipStream_t stream)
{
    const float* x   = (const float*)d_in[0];
    const int*   ei  = (const int*)d_in[1];
    const int*   bat = (const int*)d_in[2];
    const float* W1  = (const float*)d_in[3];
    const float* b1  = (const float*)d_in[4];
    const float* g1  = (const float*)d_in[5];
    const float* be1 = (const float*)d_in[6];
    const float* mm1 = (const float*)d_in[7];
    const float* mv1 = (const float*)d_in[8];
    const float* W2  = (const float*)d_in[9];
    const float* b2  = (const float*)d_in[10];
    const float* W3  = (const float*)d_in[11];
    const float* b3  = (const float*)d_in[12];
    const float* g2  = (const float*)d_in[13];
    const float* be2 = (const float*)d_in[14];
    const float* mm2 = (const float*)d_in[15];
    const float* mv2 = (const float*)d_in[16];
    const float* W4  = (const float*)d_in[17];
    const float* b4  = (const float*)d_in[18];
    float* out = (float*)d_out;

    const int N    = in_sizes[0] / 128;
    const int E    = in_sizes[1] / 2;
    const int gb   = (N + 63) / 64;       // GEMM blocks == dst bins
    const int nbin = gb;
    const int epb  = (E + EB - 1) / EB;
    const int ob   = (out_size + 255) / 256;

    char* ws = (char*)d_ws;
    size_t off = 0;
    u16* wf       = (u16*)(ws + off);  off += al256(4 * 16384 * sizeof(u16));
    u16* h1       = (u16*)(ws + off);  off += al256((size_t)N * 128 * sizeof(u16));
    u16* tb       = (u16*)(ws + off);  off += al256((size_t)N * 128 * sizeof(u16));
    int* hcnt     = (int*)(ws + off);  off += al256((size_t)EB * nbin * sizeof(int));
    int* basem    = (int*)(ws + off);  off += al256((size_t)EB * nbin * sizeof(int));
    int* segstart = (int*)(ws + off);  off += al256((size_t)(nbin + 1) * sizeof(int));
    u32* eseg     = (u32*)(ws + off);  off += al256((size_t)E * sizeof(u32));

    // A: wpack || p1hist || zero(out)
    fusedA<<<256 + EB + ob, 256, 0, stream>>>(W1, W2, W3, W4, wf,
                                              (const int2*)ei, hcnt, out,
                                              E, nbin, epb, out_size);
    // B: GEMM1 || scank
    fusedB<<<gb + 1, 256, 0, stream>>>(x, wf, b1, g1, be1, mm1, mv1, h1, N,
                                       hcnt, basem, segstart, E, nbin, gb);
    // C: GEMM2 || p1scat
    fusedC<<<gb + EB, 256, 0, stream>>>(h1, wf + 16384, b2, tb, N,
                                        (const int2*)ei, basem, eseg,
                                        E, nbin, epb, gb);
    // D: h1 = bn2(relu( (tb + gather(tb)) @ W3 + b3 ))
    aggGemm<true, false><<<gb, 256, 0, stream>>>(
        tb, segstart, eseg, wf + 2 * 16384, b3, g2, be2, mm2, mv2,
        h1, nullptr, nullptr, N);
    // E: out += group-reduce relu( (h1 + gather(h1)) @ W4 + b4 )
    aggGemm<false, true><<<gb, 256, 0, stream>>>(
        h1, segstart, eseg, wf + 3 * 16384, b4, nullptr, nullptr, nullptr, nullptr,
        nullptr, bat, out, N);
}

// Round 10
// 158.787 us; speedup vs baseline: 1.1419x; 1.0022x over previous
//
#include <hip/hip_runtime.h>
#include <hip/hip_bf16.h>

typedef unsigned short u16;
typedef unsigned int u32;
typedef __bf16 bf16_t;
typedef bf16_t bf16x8 __attribute__((ext_vector_type(8)));
typedef float f32x4 __attribute__((ext_vector_type(4)));

// Graph build is a two-level counting partition: edges -> 64-node bins
// (bin = dst>>6, one bin per aggGemm block). ALL returning atomics are LDS;
// zero per-edge global atomics (memory-side atomic wall = ~64B HBM granule
// per op, measured rounds 7/8 at ~45-57us for 640K ops).
#define EB 32            // edge-partition blocks
#define ECAP 1280        // max edges per 64-node bin (mean 816, sd ~29)

// ---------------------------------------------------------------------------
// GEMM core (global A): one wave computes 16 rows x 128 cols of
// A[M,128] @ W[128,128] via 8 col-tiles x 4 k-steps of mfma_f32_16x16x32_bf16.
// B-fragments from prepacked wf (16B/lane contiguous). Same intra-lane k map
// for A and B, so any HW k-permutation cancels.
// ---------------------------------------------------------------------------
template <bool ABF16>
__device__ __forceinline__ void gemm_core(
    const void* __restrict__ Aptr, const u16* __restrict__ wf,
    int M, int row0, int lane, f32x4 acc[8])
{
    const int r  = lane & 15;
    const int kb = lane >> 4;
    int arow = row0 + r;
    int arc  = arow < M ? arow : (M - 1);

    bf16x8 afrag[4];
    if (ABF16) {
        const u16* A = (const u16*)Aptr + (size_t)arc * 128 + kb * 8;
#pragma unroll
        for (int s = 0; s < 4; s++)
            afrag[s] = __builtin_bit_cast(bf16x8, *(const int4*)(A + s * 32));
    } else {
        const float* A = (const float*)Aptr + (size_t)arc * 128 + kb * 8;
#pragma unroll
        for (int s = 0; s < 4; s++) {
            float4 v0 = *(const float4*)(A + s * 32);
            float4 v1 = *(const float4*)(A + s * 32 + 4);
            bf16x8 t;
            t[0] = (bf16_t)v0.x; t[1] = (bf16_t)v0.y;
            t[2] = (bf16_t)v0.z; t[3] = (bf16_t)v0.w;
            t[4] = (bf16_t)v1.x; t[5] = (bf16_t)v1.y;
            t[6] = (bf16_t)v1.z; t[7] = (bf16_t)v1.w;
            afrag[s] = t;
        }
    }

#pragma unroll
    for (int ct = 0; ct < 8; ct++) acc[ct] = (f32x4){0.f, 0.f, 0.f, 0.f};

#pragma unroll
    for (int ct = 0; ct < 8; ct++) {
#pragma unroll
        for (int s = 0; s < 4; s++) {
            bf16x8 bfrag = __builtin_bit_cast(
                bf16x8, *(const int4*)(wf + (((ct << 2) + s) << 9) + (lane << 3)));
            acc[ct] = __builtin_amdgcn_mfma_f32_16x16x32_bf16(
                afrag[s], bfrag, acc[ct], 0, 0, 0);
        }
    }
}

// Epilogue: bias + relu (+ optional BN affine), store bf16.
// C/D layout (m89-verified): col = lane&15, row = (lane>>4)*4 + j
template <bool BN>
__device__ __forceinline__ void gemm_epi_store(
    f32x4 acc[8], const float* __restrict__ bias,
    const float* __restrict__ gamma, const float* __restrict__ beta,
    const float* __restrict__ mmean, const float* __restrict__ mvar,
    u16* __restrict__ obf, int M, int row0, int lane)
{
    const int crow0 = row0 + ((lane >> 4) << 2);
    const int ccol  = lane & 15;
#pragma unroll
    for (int ct = 0; ct < 8; ct++) {
        int col  = (ct << 4) + ccol;
        float b  = bias[col];
        float scale = 1.f, shift = 0.f;
        if (BN) {
            float s_ = gamma[col] / sqrtf(mvar[col] + 1e-3f);
            scale = s_;
            shift = beta[col] - mmean[col] * s_;
        }
#pragma unroll
        for (int j = 0; j < 4; j++) {
            int row = crow0 + j;
            if (row < M) {
                float v = fmaxf(acc[ct][j] + b, 0.f);
                if (BN) v = v * scale + shift;
                obf[(size_t)row * 128 + col] = __builtin_bit_cast(u16, (bf16_t)v);
            }
        }
    }
}

// ---------------------------------------------------------------------------
// Dispatch A: wpack (256 blk) || p1hist (EB blk) || zero out (rest).
// ---------------------------------------------------------------------------
__global__ __launch_bounds__(256) void fusedA(
    const float* __restrict__ W1, const float* __restrict__ W2,
    const float* __restrict__ W3, const float* __restrict__ W4,
    u16* __restrict__ wf, const int2* __restrict__ ei,
    int* __restrict__ hcnt, float* __restrict__ out,
    int E, int nbin, int epb, int outsz)
{
    if (blockIdx.x < 256) {
        int idx = blockIdx.x * 256 + threadIdx.x;          // 0..65535
        const float* Ws[4] = {W1, W2, W3, W4};
        int w  = idx >> 14;
        int e  = idx & 16383;
        int i  = e & 7;
        int l  = (e >> 3) & 63;
        int s  = (e >> 9) & 3;
        int ct = (e >> 11) & 7;
        int row = 32 * s + 8 * (l >> 4) + i;
        int col = 16 * ct + (l & 15);
        float v = Ws[w][row * 128 + col];
        wf[idx] = __builtin_bit_cast(u16, (bf16_t)v);
    } else if ((int)blockIdx.x < 256 + EB) {
        __shared__ int h[800];
        int b = blockIdx.x - 256;
        for (int i = threadIdx.x; i < nbin; i += 256) h[i] = 0;
        __syncthreads();
        int e0 = b * epb, e1 = min(e0 + epb, E);
        for (int e = e0 + threadIdx.x; e < e1; e += 256) {
            int2 p = ei[e];
            atomicAdd(&h[p.y >> 6], 1);               // LDS atomic
        }
        __syncthreads();
        for (int i = threadIdx.x; i < nbin; i += 256)
            hcnt[b * nbin + i] = h[i];
    } else {
        int i = (blockIdx.x - 256 - EB) * 256 + threadIdx.x;
        if (i < outsz) out[i] = 0.f;
    }
}

// ---------------------------------------------------------------------------
// Dispatch B: GEMM1 (x f32 -> h1 bf16, BN1)  ||  scank (1 block):
// column totals -> exclusive scan -> segstart + per-(block,bin) bases.
// ---------------------------------------------------------------------------
__global__ __launch_bounds__(256) void fusedB(
    const float* __restrict__ x, const u16* __restrict__ wf,
    const float* __restrict__ b1, const float* __restrict__ g1,
    const float* __restrict__ be1, const float* __restrict__ mm1,
    const float* __restrict__ mv1, u16* __restrict__ h1, int M,
    const int* __restrict__ hcnt, int* __restrict__ basem,
    int* __restrict__ segstart, int E, int nbin, int gb)
{
    if ((int)blockIdx.x < gb) {
        int lane = threadIdx.x & 63, wv = threadIdx.x >> 6;
        int row0 = (blockIdx.x * 4 + wv) * 16;
        f32x4 acc[8];
        gemm_core<false>(x, wf, M, row0, lane, acc);
        gemm_epi_store<true>(acc, b1, g1, be1, mm1, mv1, h1, M, row0, lane);
    } else {
        __shared__ int tot[800];
        for (int bin = threadIdx.x; bin < nbin; bin += 256) {
            int s = 0;
            for (int b = 0; b < EB; b++) s += hcnt[b * nbin + bin];
            tot[bin] = s;
        }
        __syncthreads();
        if (threadIdx.x == 0) {
            int run = 0;
            for (int i = 0; i < nbin; i++) { int v = tot[i]; tot[i] = run; run += v; }
            segstart[nbin] = E;
        }
        __syncthreads();
        for (int bin = threadIdx.x; bin < nbin; bin += 256) {
            segstart[bin] = tot[bin];
            int run = tot[bin];
            for (int b = 0; b < EB; b++) {
                basem[b * nbin + bin] = run;
                run += hcnt[b * nbin + bin];
            }
        }
    }
}

// ---------------------------------------------------------------------------
// Dispatch C: GEMM2 (h1 -> tb, no BN)  ||  p1scat (EB blocks): stream edges,
// slot from LDS running counters seeded with reserved bases, write packed
// (dstLocal<<16)|src. Same-bin edges per block -> consecutive slots.
// ---------------------------------------------------------------------------
__global__ __launch_bounds__(256) void fusedC(
    const u16* __restrict__ h1, const u16* __restrict__ wf,
    const float* __restrict__ b2, u16* __restrict__ tb, int M,
    const int2* __restrict__ ei, const int* __restrict__ basem,
    u32* __restrict__ eseg, int E, int nbin, int epb, int gb)
{
    if ((int)blockIdx.x < gb) {
        int lane = threadIdx.x & 63, wv = threadIdx.x >> 6;
        int row0 = (blockIdx.x * 4 + wv) * 16;
        f32x4 acc[8];
        gemm_core<true>(h1, wf, M, row0, lane, acc);
        gemm_epi_store<false>(acc, b2, nullptr, nullptr, nullptr, nullptr,
                              tb, M, row0, lane);
    } else {
        __shared__ int run[800];
        int b = blockIdx.x - gb;
        for (int i = threadIdx.x; i < nbin; i += 256)
            run[i] = basem[b * nbin + i];
        __syncthreads();
        int e0 = b * epb, e1 = min(e0 + epb, E);
        for (int e = e0 + threadIdx.x; e < e1; e += 256) {
            int2 p = ei[e];
            int bin = p.y >> 6;
            int pos = atomicAdd(&run[bin], 1);        // LDS atomic
            eseg[pos] = ((u32)(p.y & 63) << 16) | (u32)p.x;
        }
    }
}

// ---------------------------------------------------------------------------
// Dispatches D/E: fused GIN-aggregate + GEMM.
// Phase 0: LDS counting-sort of this bin's edge segment by dstLocal
//   (two streaming passes over eseg, no LDS staging buffer — L2-resident).
// Phase 1: 16-lane-per-node deep-batched row gathers (src ids from LDS)
//   accumulated with the self term, written to XOR-swizzled LDS A-tile.
// Phase 2: MFMA from LDS.  Epilogue: BN store (D) or group reduction (E).
// LDS budget (occupancy is the latency-hiding lever): non-RED ~19.4KB ->
// 8 blocks/CU; RED ~23.4KB -> 6 blocks/CU.
// ---------------------------------------------------------------------------
template <bool BN_, bool RED>
__global__ __launch_bounds__(256) void aggGemm(
    const u16* __restrict__ t, const int* __restrict__ segstart,
    const u32* __restrict__ eseg,
    const u16* __restrict__ wf, const float* __restrict__ bias,
    const float* __restrict__ gamma, const float* __restrict__ beta,
    const float* __restrict__ mmean, const float* __restrict__ mvar,
    u16* __restrict__ obf, const int* __restrict__ batch,
    float* __restrict__ out, int N)
{
    constexpr int GSPAN = 8;
    __shared__ u16 ldsA[64 * 128];
    __shared__ u16 slist[ECAP];
    __shared__ int cnt[64];
    __shared__ int sstart[65];
    __shared__ float grp[RED ? (GSPAN * 128) : 1];

    const int row0blk = blockIdx.x * 64;

    // ---- Phase 0: local counting sort of this bin's edges ----
    int segb = segstart[blockIdx.x];
    int k    = segstart[blockIdx.x + 1] - segb;
    if (k > ECAP) k = ECAP;              // impossible statistically; safety
    if (threadIdx.x < 64) cnt[threadIdx.x] = 0;
    __syncthreads();
    for (int i = threadIdx.x; i < k; i += 256)
        atomicAdd(&cnt[eseg[segb + i] >> 16], 1);
    __syncthreads();
    if (threadIdx.x == 0) {
        int run = 0;
#pragma unroll
        for (int d = 0; d < 64; d++) {
            sstart[d] = run;
            run += cnt[d];
            cnt[d] = sstart[d];          // becomes running placement counter
        }
        sstart[64] = run;
    }
    __syncthreads();
    for (int i = threadIdx.x; i < k; i += 256) {
        u32 v = eseg[segb + i];
        int pos = atomicAdd(&cnt[v >> 16], 1);
        slist[pos] = (u16)(v & 0xffffu);
    }
    __syncthreads();

    // ---- Phase 1: gather rows into swizzled LDS A-tile ----
    const int sub = threadIdx.x >> 4;       // 0..15: node within pass
    const int c   = threadIdx.x & 15;       // 16B chunk within row
    const int c8  = c << 3;

#pragma unroll
    for (int pass = 0; pass < 4; pass++) {
        int rl   = pass * 16 + sub;         // 0..63 local row
        int node = row0blk + rl;
        float acc[8];
        if (node < N) {
            bf16x8 s8 = __builtin_bit_cast(
                bf16x8, *(const int4*)(t + (size_t)node * 128 + c8));
#pragma unroll
            for (int j = 0; j < 8; j++) acc[j] = (float)s8[j];

            int i = sstart[rl], end = sstart[rl + 1];
            while (i + 8 <= end) {
                int idx[8];
#pragma unroll
                for (int u = 0; u < 8; u++) idx[u] = slist[i + u];
                int4 rows[8];
#pragma unroll
                for (int u = 0; u < 8; u++)
                    rows[u] = *(const int4*)(t + (size_t)idx[u] * 128 + c8);
#pragma unroll
                for (int u = 0; u < 8; u++) {
                    bf16x8 v = __builtin_bit_cast(bf16x8, rows[u]);
#pragma unroll
                    for (int j = 0; j < 8; j++) acc[j] += (float)v[j];
                }
                i += 8;
            }
            if (i + 4 <= end) {
                int idx[4];
#pragma unroll
                for (int u = 0; u < 4; u++) idx[u] = slist[i + u];
                int4 rows[4];
#pragma unroll
                for (int u = 0; u < 4; u++)
                    rows[u] = *(const int4*)(t + (size_t)idx[u] * 128 + c8);
#pragma unroll
                for (int u = 0; u < 4; u++) {
                    bf16x8 v = __builtin_bit_cast(bf16x8, rows[u]);
#pragma unroll
                    for (int j = 0; j < 8; j++) acc[j] += (float)v[j];
                }
                i += 4;
            }
            for (; i < end; ++i) {
                int src = slist[i];
                bf16x8 v = __builtin_bit_cast(bf16x8,
                    *(const int4*)(t + (size_t)src * 128 + c8));
#pragma unroll
                for (int j = 0; j < 8; j++) acc[j] += (float)v[j];
            }
        } else {
#pragma unroll
            for (int j = 0; j < 8; j++) acc[j] = 0.f;
        }
        bf16x8 o;
#pragma unroll
        for (int j = 0; j < 8; j++) o[j] = (bf16_t)acc[j];
        *(int4*)((char*)ldsA + rl * 256 + ((c ^ (rl & 7)) << 4)) =
            __builtin_bit_cast(int4, o);
    }

    if (RED) {
        for (int i = threadIdx.x; i < GSPAN * 128; i += 256) grp[i] = 0.f;
    }
    __syncthreads();

    // ---- Phase 2: GEMM from swizzled LDS ----
    const int lane = threadIdx.x & 63;
    const int wv   = threadIdx.x >> 6;
    const int r    = lane & 15;
    const int kb   = lane >> 4;
    const int rl   = wv * 16 + r;

    bf16x8 afrag[4];
#pragma unroll
    for (int s = 0; s < 4; s++)
        afrag[s] = __builtin_bit_cast(
            bf16x8, *(const int4*)((const char*)ldsA + rl * 256 +
                                   ((((s << 2) + kb) ^ (rl & 7)) << 4)));

    f32x4 acc[8];
#pragma unroll
    for (int ct = 0; ct < 8; ct++) acc[ct] = (f32x4){0.f, 0.f, 0.f, 0.f};
#pragma unroll
    for (int ct = 0; ct < 8; ct++) {
#pragma unroll
        for (int s = 0; s < 4; s++) {
            bf16x8 bfrag = __builtin_bit_cast(
                bf16x8, *(const int4*)(wf + (((ct << 2) + s) << 9) + (lane << 3)));
            acc[ct] = __builtin_amdgcn_mfma_f32_16x16x32_bf16(
                afrag[s], bfrag, acc[ct], 0, 0, 0);
        }
    }

    const int row0 = row0blk + wv * 16;
    if constexpr (!RED) {
        gemm_epi_store<BN_>(acc, bias, gamma, beta, mmean, mvar, obf, N, row0, lane);
    } else {
        int gfirst = batch[row0blk];
        int lastr  = row0blk + 63 < N - 1 ? row0blk + 63 : N - 1;
        int glast  = batch[lastr];
        const int crow0 = row0 + ((lane >> 4) << 2);
        const int ccol  = lane & 15;
        int bj[4];
#pragma unroll
        for (int j = 0; j < 4; j++) {
            int row = crow0 + j;
            bj[j] = (row < N) ? batch[row] : -1;
        }
        if (glast - gfirst < GSPAN) {
#pragma unroll
            for (int ct = 0; ct < 8; ct++) {
                int col = (ct << 4) + ccol;
                float b = bias[col];
                float run = 0.f;
                int gp = -1;
#pragma unroll
                for (int j = 0; j < 4; j++) {
                    if (bj[j] < 0) continue;
                    float v = fmaxf(acc[ct][j] + b, 0.f);
                    if (bj[j] != gp) {
                        if (gp >= 0) atomicAdd(&grp[(gp - gfirst) * 128 + col], run);
                        run = 0.f;
                        gp  = bj[j];
                    }
                    run += v;
                }
                if (gp >= 0) atomicAdd(&grp[(gp - gfirst) * 128 + col], run);
            }
            __syncthreads();
            int span = glast - gfirst + 1;
            for (int i = threadIdx.x; i < span * 128; i += 256) {
                float v = grp[i];
                if (v != 0.f) atomicAdd(out + (size_t)gfirst * 128 + i, v);
            }
        } else {
#pragma unroll
            for (int ct = 0; ct < 8; ct++) {
                int col = (ct << 4) + ccol;
                float b = bias[col];
                float run = 0.f;
                int gp = -1;
#pragma unroll
                for (int j = 0; j < 4; j++) {
                    if (bj[j] < 0) continue;
                    float v = fmaxf(acc[ct][j] + b, 0.f);
                    if (bj[j] != gp) {
                        if (gp >= 0) atomicAdd(out + (size_t)gp * 128 + col, run);
                        run = 0.f;
                        gp  = bj[j];
                    }
                    run += v;
                }
                if (gp >= 0) atomicAdd(out + (size_t)gp * 128 + col, run);
            }
        }
    }
}

// ---------------------------------------------------------------------------
static inline size_t al256(size_t x) { return (x + 255) & ~(size_t)255; }

extern "C" void kernel_launch(void* const* d_in, const int* in_sizes, int n_in,
                              void* d_out, int out_size, void* d_ws, size_t ws_size,
                              hipStream_t stream)
{
    const float* x   = (const float*)d_in[0];
    const int*   ei  = (const int*)d_in[1];
    const int*   bat = (const int*)d_in[2];
    const float* W1  = (const float*)d_in[3];
    const float* b1  = (const float*)d_in[4];
    const float* g1  = (const float*)d_in[5];
    const float* be1 = (const float*)d_in[6];
    const float* mm1 = (const float*)d_in[7];
    const float* mv1 = (const float*)d_in[8];
    const float* W2  = (const float*)d_in[9];
    const float* b2  = (const float*)d_in[10];
    const float* W3  = (const float*)d_in[11];
    const float* b3  = (const float*)d_in[12];
    const float* g2  = (const float*)d_in[13];
    const float* be2 = (const float*)d_in[14];
    const float* mm2 = (const float*)d_in[15];
    const float* mv2 = (const float*)d_in[16];
    const float* W4  = (const float*)d_in[17];
    const float* b4  = (const float*)d_in[18];
    float* out = (float*)d_out;

    const int N    = in_sizes[0] / 128;
    const int E    = in_sizes[1] / 2;
    const int gb   = (N + 63) / 64;       // GEMM blocks == dst bins
    const int nbin = gb;
    const int epb  = (E + EB - 1) / EB;
    const int ob   = (out_size + 255) / 256;

    char* ws = (char*)d_ws;
    size_t off = 0;
    u16* wf       = (u16*)(ws + off);  off += al256(4 * 16384 * sizeof(u16));
    u16* h1       = (u16*)(ws + off);  off += al256((size_t)N * 128 * sizeof(u16));
    u16* tb       = (u16*)(ws + off);  off += al256((size_t)N * 128 * sizeof(u16));
    int* hcnt     = (int*)(ws + off);  off += al256((size_t)EB * nbin * sizeof(int));
    int* basem    = (int*)(ws + off);  off += al256((size_t)EB * nbin * sizeof(int));
    int* segstart = (int*)(ws + off);  off += al256((size_t)(nbin + 1) * sizeof(int));
    u32* eseg     = (u32*)(ws + off);  off += al256((size_t)E * sizeof(u32));

    // A: wpack || p1hist || zero(out)
    fusedA<<<256 + EB + ob, 256, 0, stream>>>(W1, W2, W3, W4, wf,
                                              (const int2*)ei, hcnt, out,
                                              E, nbin, epb, out_size);
    // B: GEMM1 || scank
    fusedB<<<gb + 1, 256, 0, stream>>>(x, wf, b1, g1, be1, mm1, mv1, h1, N,
                                       hcnt, basem, segstart, E, nbin, gb);
    // C: GEMM2 || p1scat
    fusedC<<<gb + EB, 256, 0, stream>>>(h1, wf + 16384, b2, tb, N,
                                        (const int2*)ei, basem, eseg,
                                        E, nbin, epb, gb);
    // D: h1 = bn2(relu( (tb + gather(tb)) @ W3 + b3 ))
    aggGemm<true, false><<<gb, 256, 0, stream>>>(
        tb, segstart, eseg, wf + 2 * 16384, b3, g2, be2, mm2, mv2,
        h1, nullptr, nullptr, N);
    // E: out += group-reduce relu( (h1 + gather(h1)) @ W4 + b4 )
    aggGemm<false, true><<<gb, 256, 0, stream>>>(
        h1, segstart, eseg, wf + 3 * 16384, b4, nullptr, nullptr, nullptr, nullptr,
        nullptr, bat, out, N);
}